// Round 7
// baseline (485.460 us; speedup 1.0000x reference)
//
#include <hip/hip_runtime.h>
#include <math.h>
#include <stdint.h>

// Problem constants (match reference)
#define Bb 2
#define Lq 2048
#define Dm 2048
#define Hh 16
#define DH 128
#define DREL 64
#define KTOP 512   // 0.25 * L

#define NEG_INF (-__builtin_huge_valf())

typedef __attribute__((ext_vector_type(8))) short bf16x8;   // 8 bf16 (4 VGPRs)
typedef __attribute__((ext_vector_type(4))) float f32x4;

static __device__ __forceinline__ unsigned short f2bf(float f) {
  unsigned int u = __float_as_uint(f);
  u += 0x7fffu + ((u >> 16) & 1u);   // RNE
  return (unsigned short)(u >> 16);
}

// async global->LDS, 16B per lane; LDS dest = wave-uniform base + lane*16
static __device__ __forceinline__ void gload16(const void* g, void* lds) {
  __builtin_amdgcn_global_load_lds(
      (const __attribute__((address_space(1))) uint32_t*)(uintptr_t)g,
      (__attribute__((address_space(3))) uint32_t*)(uint32_t)(uintptr_t)lds,
      16, 0, 0);
}

// ---------------------------------------------------------------------------
// fp32 -> bf16 elementwise with optional scale (n8 = n/8)
// ---------------------------------------------------------------------------
__global__ __launch_bounds__(256) void conv_bf16(const float* __restrict__ in,
                                                 unsigned short* __restrict__ out,
                                                 int n8, float scale) {
  const int i = blockIdx.x * 256 + threadIdx.x;
  if (i >= n8) return;
  const float4 f0 = ((const float4*)in)[2 * i];
  const float4 f1 = ((const float4*)in)[2 * i + 1];
  bf16x8 o;
  o[0] = (short)f2bf(f0.x * scale); o[1] = (short)f2bf(f0.y * scale);
  o[2] = (short)f2bf(f0.z * scale); o[3] = (short)f2bf(f0.w * scale);
  o[4] = (short)f2bf(f1.x * scale); o[5] = (short)f2bf(f1.y * scale);
  o[6] = (short)f2bf(f1.z * scale); o[7] = (short)f2bf(f1.w * scale);
  *(bf16x8*)(out + 8 * (size_t)i) = o;
}

// 4 weight matrices -> bf16, one launch (blockIdx.y selects); w0 gets scale s0.
__global__ __launch_bounds__(256) void conv_bf16_w4(const float* __restrict__ w0,
                                                    const float* __restrict__ w1,
                                                    const float* __restrict__ w2,
                                                    const float* __restrict__ w3,
                                                    unsigned short* __restrict__ out,
                                                    float s0) {
  const int sel = blockIdx.y;
  const float* in = (sel == 0) ? w0 : (sel == 1) ? w1 : (sel == 2) ? w2 : w3;
  const float scale = (sel == 0) ? s0 : 1.0f;
  const int i = blockIdx.x * 256 + threadIdx.x;   // grid.x = ND/8/256 exact
  const float4 f0 = ((const float4*)in)[2 * i];
  const float4 f1 = ((const float4*)in)[2 * i + 1];
  bf16x8 o;
  o[0] = (short)f2bf(f0.x * scale); o[1] = (short)f2bf(f0.y * scale);
  o[2] = (short)f2bf(f0.z * scale); o[3] = (short)f2bf(f0.w * scale);
  o[4] = (short)f2bf(f1.x * scale); o[5] = (short)f2bf(f1.y * scale);
  o[6] = (short)f2bf(f1.z * scale); o[7] = (short)f2bf(f1.w * scale);
  *(bf16x8*)(out + (size_t)sel * Dm * Dm + 8 * (size_t)i) = o;
}

// ---------------------------------------------------------------------------
// Triple-buffered bf16 GEMM: 256 thr (4 waves 2x2), 128x128 tile, BK=32,
// 3 blocks/CU (48 KiB LDS x3 = 144 <= 160). C[M,N] = A[M,K] @ W[N,K]^T.
//
// Pipeline (prefetch depth 2): per iteration t,
//   ST(tile t+2 -> buf (t+2)%3)  [4 gload16]
//   s_waitcnt vmcnt(8) + s_barrier   // t+1,t+2 in flight; tile t landed
//   4x LD_A + 2x(2 LD_B + 8 MFMA)    // compute tile t from buf t%3
//   s_barrier
// Tail: t=nt-2 -> vmcnt(4); t=nt-1 -> vmcnt(0). Never vmcnt(0) elsewhere.
// WAR: ST(t+2) targets (t+2)%3 == (t-1)%3 = tile t-1's buffer; all waves'
// ds_reads of it completed before the end-of-(t-1) barrier (lgkmcnt before
// MFMA consume). vmcnt is per-wave; each ST = 4 increments per wave; barrier
// makes the per-wave guarantee collective.
// ROUND-6 BUG FIX: sb must be (cb+2)%3; old expression gave sb=2 when cb=1
// (overwrote the NEXT tile's buffer every 3rd iteration -> absmax 53.7).
// ---------------------------------------------------------------------------
template <bool BF16OUT>
__global__ __launch_bounds__(256, 3) void gemmT(const unsigned short* __restrict__ A,
                                                const unsigned short* __restrict__ W,
                                                void* __restrict__ Cv,
                                                int M, int N, int Kd) {
  __shared__ unsigned short As[3][128][32];   // 24 KiB
  __shared__ unsigned short Bs[3][128][32];   // 24 KiB

  const int tid = threadIdx.x;
  const int lane = tid & 63;
  const int w = tid >> 6;       // wave 0..3
  const int l15 = lane & 15;
  const int quad = lane >> 4;
  const int wm = w >> 1;        // 0..1 -> 64-row half
  const int wn = w & 1;         // 0..1 -> 64-col half

  // T1: XCD column-chunk mapping (B-panel stays hot in the XCD L2)
  const int gy = M >> 7;
  const int nwg = gy * (N >> 7);
  const int cpx = nwg >> 3;                 // nwg % 8 == 0 for our shapes
  const int bid = (int)blockIdx.x;
  const int lin = (bid & 7) * cpx + (bid >> 3);
  const int by = lin % gy, bx = lin / gy;
  const int m0 = by * 128, n0 = bx * 128;

  // staging: one gload16 call-site = 4 waves x 16 rows x 4 slots (64 rows).
  // per-lane row = tid>>2, phys 16B slot = tid&3.
  // Read swizzle phys = quad ^ ((l15>>1)&3); inverse on the global source:
  // logical slot = (tid&3) ^ ((row>>1)&3) = (tid&3) ^ ((tid>>3)&3)
  // (row base +64 shifts (row>>1) by 32 == 0 mod 4 -> same formula).
  const int srow = tid >> 2;
  const int sslot = (tid & 3) ^ ((tid >> 3) & 3);
  const unsigned short* aB = A + (size_t)(m0 + srow) * Kd + sslot * 8;
  const unsigned short* bB = W + (size_t)(n0 + srow) * Kd + sslot * 8;
  const size_t hstep = (size_t)64 * Kd;

  f32x4 acc[4][4];
#pragma unroll
  for (int i = 0; i < 4; ++i)
#pragma unroll
    for (int j = 0; j < 4; ++j) acc[i][j] = (f32x4){0.f, 0.f, 0.f, 0.f};

  bf16x8 af[4], bfr[2];
  const int rswz = (quad ^ ((l15 >> 1) & 3)) * 8;   // proven 0-conflict (r3/r5)

#define ST(BUF, T)                                                          \
  do {                                                                      \
    const size_t ko = (size_t)(T) * 32;                                     \
    gload16(aB + ko, &As[BUF][w * 16][0]);                                  \
    gload16(aB + hstep + ko, &As[BUF][64 + w * 16][0]);                     \
    gload16(bB + ko, &Bs[BUF][w * 16][0]);                                  \
    gload16(bB + hstep + ko, &Bs[BUF][64 + w * 16][0]);                     \
  } while (0)

#define LD_A(BUF)                                                           \
  _Pragma("unroll") for (int mi = 0; mi < 4; ++mi)                          \
      af[mi] = *(const bf16x8*)&As[BUF][wm * 64 + mi * 16 + l15][rswz];

#define LD_B(BUF, NP)                                                       \
  _Pragma("unroll") for (int ni = 0; ni < 2; ++ni)                          \
      bfr[ni] = *(const bf16x8*)&Bs[BUF][wn * 64 + ((NP) * 2 + ni) * 16 + l15][rswz];

#define MFMA_NP(NP)                                                         \
  do {                                                                      \
    __builtin_amdgcn_s_setprio(1);                                          \
    _Pragma("unroll") for (int mi = 0; mi < 4; ++mi)                        \
        _Pragma("unroll") for (int ni = 0; ni < 2; ++ni)                    \
            acc[mi][(NP) * 2 + ni] = __builtin_amdgcn_mfma_f32_16x16x32_bf16( \
                af[mi], bfr[ni], acc[mi][(NP) * 2 + ni], 0, 0, 0);          \
    __builtin_amdgcn_s_setprio(0);                                          \
  } while (0)

  // prologue: tiles 0,1 -> bufs 0,1 (8 loads in flight per wave)
  ST(0, 0);
  ST(1, 1);

  const int nt = Kd >> 5;   // 64
  int cb = 0;               // compute buffer = t % 3
  for (int t = 0; t < nt; ++t) {
    if (t + 2 < nt) {
      const int sb = (cb >= 1) ? (cb - 1) : 2;   // (cb+2)%3  [FIXED]
      ST(sb, t + 2);
      asm volatile("s_waitcnt vmcnt(8)\ns_barrier" ::: "memory");
    } else if (t + 1 < nt) {
      asm volatile("s_waitcnt vmcnt(4)\ns_barrier" ::: "memory");
    } else {
      asm volatile("s_waitcnt vmcnt(0)\ns_barrier" ::: "memory");
    }
    LD_A(cb);
    LD_B(cb, 0);
    MFMA_NP(0);
    LD_B(cb, 1);
    MFMA_NP(1);
    asm volatile("s_barrier" ::: "memory");
    cb = (cb + 1 == 3) ? 0 : cb + 1;
  }
#undef ST
#undef LD_A
#undef LD_B
#undef MFMA_NP

#pragma unroll
  for (int im = 0; im < 4; ++im) {
#pragma unroll
    for (int in = 0; in < 4; ++in) {
      const int col = n0 + wn * 64 + in * 16 + l15;
#pragma unroll
      for (int r = 0; r < 4; ++r) {
        const int row = m0 + wm * 64 + im * 16 + quad * 4 + r;
        if (BF16OUT)
          ((unsigned short*)Cv)[(size_t)row * N + col] = f2bf(acc[im][in][r]);
        else
          ((float*)Cv)[(size_t)row * N + col] = acc[im][in][r];
      }
    }
  }
}

// ---------------------------------------------------------------------------
// Split-K fp32 rel projection, q and k fused via blockIdx.z.
// ---------------------------------------------------------------------------
#define RKS 8
__global__ __launch_bounds__(256) void relproj2(const float* __restrict__ A,
                                                const float* __restrict__ Wqr,
                                                const float* __restrict__ Wkr,
                                                float* __restrict__ partq,
                                                float* __restrict__ partk, int M) {
  const float* W = blockIdx.z ? Wkr : Wqr;
  float* part = blockIdx.z ? partk : partq;
  __shared__ float As[16][128];
  __shared__ float Bs[16][64];
  const int ks = blockIdx.x;
  const int m0 = blockIdx.y * 128;
  const int tid = threadIdx.x;
  const int tx = tid & 15;
  const int ty = tid >> 4;
  const int lr = tid >> 1, lk = (tid & 1) * 8;
  const int wr = tid >> 2, wk = (tid & 3) * 4;

  float acc[8][4];
#pragma unroll
  for (int i = 0; i < 8; ++i)
#pragma unroll
    for (int j = 0; j < 4; ++j) acc[i][j] = 0.f;

  const int k00 = ks * (Dm / RKS);
  for (int k0 = k00; k0 < k00 + Dm / RKS; k0 += 16) {
    {
      const float* ap = A + (size_t)(m0 + lr) * Dm + k0 + lk;
      float4 a0 = *(const float4*)(ap);
      float4 a1 = *(const float4*)(ap + 4);
      As[lk + 0][lr] = a0.x; As[lk + 1][lr] = a0.y;
      As[lk + 2][lr] = a0.z; As[lk + 3][lr] = a0.w;
      As[lk + 4][lr] = a1.x; As[lk + 5][lr] = a1.y;
      As[lk + 6][lr] = a1.z; As[lk + 7][lr] = a1.w;
    }
    {
      const float* bp = W + (size_t)wr * Dm + k0 + wk;
      float4 b0 = *(const float4*)(bp);
      Bs[wk + 0][wr] = b0.x; Bs[wk + 1][wr] = b0.y;
      Bs[wk + 2][wr] = b0.z; Bs[wk + 3][wr] = b0.w;
    }
    __syncthreads();
#pragma unroll
    for (int kk = 0; kk < 16; ++kk) {
      float af[8], bf[4];
#pragma unroll
      for (int i = 0; i < 8; ++i) af[i] = As[kk][ty * 8 + i];
#pragma unroll
      for (int j = 0; j < 4; ++j) bf[j] = Bs[kk][tx * 4 + j];
#pragma unroll
      for (int i = 0; i < 8; ++i)
#pragma unroll
        for (int j = 0; j < 4; ++j) acc[i][j] += af[i] * bf[j];
    }
    __syncthreads();
  }

#pragma unroll
  for (int i = 0; i < 8; ++i) {
    float* pp = part + ((size_t)ks * M + m0 + ty * 8 + i) * DREL + tx * 4;
    *(float4*)pp = make_float4(acc[i][0], acc[i][1], acc[i][2], acc[i][3]);
  }
}

__global__ __launch_bounds__(256) void relreduce(const float* __restrict__ pq,
                                                 const float* __restrict__ pk,
                                                 float* __restrict__ qrel,
                                                 float* __restrict__ krel, int n4) {
  const int i = blockIdx.x * 256 + threadIdx.x;
  if (i >= n4) return;
  float4 sq = make_float4(0, 0, 0, 0), sk = sq;
  for (int s = 0; s < RKS; ++s) {
    float4 a = ((const float4*)pq)[(size_t)s * n4 + i];
    float4 b = ((const float4*)pk)[(size_t)s * n4 + i];
    sq.x += a.x; sq.y += a.y; sq.z += a.z; sq.w += a.w;
    sk.x += b.x; sk.y += b.y; sk.z += b.z; sk.w += b.w;
  }
  ((float4*)qrel)[i] = sq;
  ((float4*)krel)[i] = sk;
}

// ---------------------------------------------------------------------------
// Dense triangular rel-score GEMM: S[b][q][j] = (qrel[b,q,:]·krel[b,j,:])*DREL^-0.5
// ---------------------------------------------------------------------------
__global__ __launch_bounds__(256) void relscore(const float* __restrict__ qrel,
                                                const float* __restrict__ krel,
                                                float* __restrict__ S) {
  const int jt = blockIdx.x, qt = blockIdx.y, b = blockIdx.z;
  if (jt > qt) return;
  __shared__ float As[16][128];
  __shared__ float Bs[16][128];
  const int tid = threadIdx.x;
  const int q0 = qt * 128, j0 = jt * 128;
  const int tx = tid & 15, ty = tid >> 4;
  const int lr = tid >> 1, lk = (tid & 1) * 8;
  const float* Ab = qrel + (size_t)b * Lq * DREL;
  const float* Kb = krel + (size_t)b * Lq * DREL;

  float acc[8][8];
#pragma unroll
  for (int i = 0; i < 8; ++i)
#pragma unroll
    for (int j = 0; j < 8; ++j) acc[i][j] = 0.f;

  for (int k0 = 0; k0 < DREL; k0 += 16) {
    {
      const float* ap = Ab + (size_t)(q0 + lr) * DREL + k0 + lk;
      float4 a0 = *(const float4*)(ap);
      float4 a1 = *(const float4*)(ap + 4);
      As[lk + 0][lr] = a0.x; As[lk + 1][lr] = a0.y;
      As[lk + 2][lr] = a0.z; As[lk + 3][lr] = a0.w;
      As[lk + 4][lr] = a1.x; As[lk + 5][lr] = a1.y;
      As[lk + 6][lr] = a1.z; As[lk + 7][lr] = a1.w;
    }
    {
      const float* bp = Kb + (size_t)(j0 + lr) * DREL + k0 + lk;
      float4 b0 = *(const float4*)(bp);
      float4 b1 = *(const float4*)(bp + 4);
      Bs[lk + 0][lr] = b0.x; Bs[lk + 1][lr] = b0.y;
      Bs[lk + 2][lr] = b0.z; Bs[lk + 3][lr] = b0.w;
      Bs[lk + 4][lr] = b1.x; Bs[lk + 5][lr] = b1.y;
      Bs[lk + 6][lr] = b1.z; Bs[lk + 7][lr] = b1.w;
    }
    __syncthreads();
#pragma unroll
    for (int kk = 0; kk < 16; ++kk) {
      float af[8], bf[8];
#pragma unroll
      for (int i = 0; i < 8; ++i) af[i] = As[kk][ty * 8 + i];
#pragma unroll
      for (int j = 0; j < 8; ++j) bf[j] = Bs[kk][tx * 8 + j];
#pragma unroll
      for (int i = 0; i < 8; ++i)
#pragma unroll
        for (int j = 0; j < 8; ++j) acc[i][j] += af[i] * bf[j];
    }
    __syncthreads();
  }

  const float sc = 0.125f;  // DREL^-0.5
#pragma unroll
  for (int i = 0; i < 8; ++i) {
    float* cp = S + ((size_t)b * Lq + q0 + ty * 8 + i) * Lq + j0 + tx * 8;
    ((float4*)cp)[0] = make_float4(acc[i][0] * sc, acc[i][1] * sc, acc[i][2] * sc, acc[i][3] * sc);
    ((float4*)cp)[1] = make_float4(acc[i][4] * sc, acc[i][5] * sc, acc[i][6] * sc, acc[i][7] * sc);
  }
}

// ---------------------------------------------------------------------------
// Wave-per-row exact top-K select + mask emission, all in registers.
// ---------------------------------------------------------------------------
__global__ __launch_bounds__(256) void relselect(const float* __restrict__ S,
                                                 uint32_t* __restrict__ mask) {
  const int w = threadIdx.x >> 6;
  const int lane = threadIdx.x & 63;
  const int ridx = blockIdx.x * 4 + w;      // = b*Lq + qi
  const int qi = ridx & (Lq - 1);
  const int n = qi + 1;
  const float* srow = S + (size_t)ridx * Lq;

  uint32_t keys[32];
#pragma unroll
  for (int t = 0; t < 32; ++t) {
    const int j = t * 64 + lane;
    const uint32_t u = __float_as_uint(srow[j]);
    const uint32_t k = (u & 0x80000000u) ? ~u : (u | 0x80000000u);
    keys[t] = (j < n) ? k : 0u;   // 0 never matches any candidate prefix
  }

  uint32_t kth = 0u;
  if (n > KTOP) {
    uint32_t pref = 0u;
    int rem = KTOP;
    for (int bit = 31; bit >= 0; --bit) {
      const uint32_t cand = pref | (1u << bit);
      const uint32_t lim = 1u << bit;
      int c = 0;
#pragma unroll
      for (int t = 0; t < 32; ++t) c += ((keys[t] ^ cand) < lim) ? 1 : 0;
      c += __shfl_xor(c, 1);
      c += __shfl_xor(c, 2);
      c += __shfl_xor(c, 4);
      c += __shfl_xor(c, 8);
      c += __shfl_xor(c, 16);
      c += __shfl_xor(c, 32);
      if (c >= rem) pref = cand;
      else rem -= c;
    }
    kth = pref;
  }

  uint32_t* mrow = mask + (size_t)ridx * (Lq / 32);
#pragma unroll
  for (int t = 0; t < 32; ++t) {
    const int j = t * 64 + lane;
    const bool ok = (j < n) && (keys[t] >= kth || j == qi);  // kth=0 -> causal-only
    const unsigned long long bal = __ballot(ok);
    if (lane == 0) {
      mrow[2 * t] = (uint32_t)bal;
      mrow[2 * t + 1] = (uint32_t)(bal >> 32);
    }
  }
}

// ---------------------------------------------------------------------------
// Flash attention v3: TK=64 tiles, double-buffered LDS with reg-staged
// async split (T14), one barrier per tile, setprio around MFMA cluster (T5).
// Q is pre-scaled by DH^-0.5*log2(e) at weight-conversion time.
// Reads fused QKV buffer with row stride 3*Dm (q at +0, k at +2048, v at +4096).
// ---------------------------------------------------------------------------
#define ATQ 128
#define TK 64
__global__ __launch_bounds__(512, 4) void attn_flash3(const unsigned short* __restrict__ qkv,
                                                      const uint32_t* __restrict__ mask,
                                                      unsigned short* __restrict__ ctx) {
  __shared__ unsigned short Ks[2][TK][136];      // 34816 B
  __shared__ unsigned short Vt[2][2][64][72];    // 36864 B  [buf][half][d>>1][(d&1)*32+slot]
  __shared__ uint32_t mw[2][ATQ][2];             //  2048 B

  // z=0: heavy-first; z=1: light-first -> co-resident pairs (id, id+256) balance
  const int qt = (blockIdx.z == 0) ? ((Lq / ATQ) - 1 - (int)blockIdx.x) : (int)blockIdx.x;
  const int h = blockIdx.y;
  const int b = blockIdx.z;
  const int tid = threadIdx.x;
  const int w = tid >> 6;          // wave 0..7
  const int lane = tid & 63;
  const int l15 = lane & 15;
  const int quad = lane >> 4;
  const int q0 = qt * ATQ;
  const int STR = 3 * Dm;

  const unsigned short* kbp = qkv + 2048;
  const unsigned short* vbp = qkv + 4096;

  // Q fragment (already scaled by DH^-0.5*log2e via Wq conversion)
  const int myq = q0 + w * 16 + l15;
  const unsigned short* qrow = qkv + (size_t)(b * Lq + myq) * STR + h * DH;
  bf16x8 bq[4];
#pragma unroll
  for (int kk = 0; kk < 4; ++kk) bq[kk] = *(const bf16x8*)(qrow + kk * 32 + quad * 8);

  f32x4 O[8];  // O^T: O[f][r] = ctx[q=l15][f*16 + quad*4 + r]
#pragma unroll
  for (int f = 0; f < 8; ++f) O[f] = (f32x4){0.f, 0.f, 0.f, 0.f};
  float l_lane = 0.f;

  const int nt = (q0 + ATQ) / TK;   // = 2*qt + 2

  // staging geometry: waves 0-3 stage K + mask, waves 4-7 stage V
  const int skey = (tid & 255) >> 2;     // K: key 0..63
  const int scg  = tid & 3;              // K: dim group of 32
  const int mq   = (tid & 255) >> 1;     // mask: q row 0..127
  const int msel = tid & 1;
  const int tv = tid - 256;
  const int vkp = tv & 31;               // V: key pair 0..31
  const int vdg = (tv >> 5) & 7;         // V: dim group of 16
  const int vhalf = vkp >> 4;
  const int vkp16 = vkp & 15;
  const int dwc = ((vkp16 >> 1) & 3) * 4 + (vkp16 >> 3) * 2 + (vkp16 & 1);

  const uint32_t* mrow_base = mask + (size_t)(b * Lq + q0 + mq) * (Lq / 32) + msel;
  const unsigned short* krow_base = kbp + (size_t)(b * Lq + skey) * STR + h * DH + scg * 32;
  const unsigned short* vrow_base = vbp + (size_t)(b * Lq + 2 * vkp) * STR + h * DH + vdg * 16;

  bf16x8 r0, r1, r2, r3;
  uint32_t mreg = 0;

#define LOADREGS(KT)                                                       \
  do {                                                                     \
    const int kbase_ = (KT) * TK;                                          \
    if (tid < 256) {                                                       \
      const unsigned short* kr = krow_base + (size_t)kbase_ * STR;         \
      r0 = *(const bf16x8*)(kr);                                           \
      r1 = *(const bf16x8*)(kr + 8);                                       \
      r2 = *(const bf16x8*)(kr + 16);                                      \
      r3 = *(const bf16x8*)(kr + 24);                                      \
      mreg = mrow_base[(KT) * 2];                                          \
    } else {                                                               \
      const unsigned short* vr = vrow_base + (size_t)kbase_ * STR;         \
      r0 = *(const bf16x8*)(vr);                                           \
      r1 = *(const bf16x8*)(vr + 8);                                       \
      r2 = *(const bf16x8*)(vr + STR);                                     \
      r3 = *(const bf16x8*)(vr + STR + 8);                                 \
    }                                                                      \
  } while (0)

#define WRITELDS(BUF)                                                      \
  do {                                                                     \
    if (tid < 256) {                                                       \
      *(bf16x8*)&Ks[BUF][skey][scg * 32 + 0]  = r0;                        \
      *(bf16x8*)&Ks[BUF][skey][scg * 32 + 8]  = r1;                        \
      *(bf16x8*)&Ks[BUF][skey][scg * 32 + 16] = r2;                        \
      *(bf16x8*)&Ks[BUF][skey][scg * 32 + 24] = r3;                        \
      mw[BUF][mq][msel] = mreg;                                            \
    } else {                                                               \
      _Pragma("unroll") for (int i = 0; i < 8; ++i) {                      \
        const int d = vdg * 16 + i;                                        \
        const uint32_t pk = (uint32_t)(unsigned short)r0[i] |              \
                            ((uint32_t)(unsigned short)r2[i] << 16);       \
        ((uint32_t*)&Vt[BUF][vhalf][d >> 1][0])[(d & 1) * 16 + dwc] = pk;  \
      }                                                                    \
      _Pragma("unroll") for (int i = 0; i < 8; ++i) {                      \
        const int d = vdg * 16 + 8 + i;                                    \
        const uint32_t pk = (uint32_t)(unsigned short)r1[i] |              \
                            ((uint32_t)(unsigned short)r3[i] << 16);       \
        ((uint32_t*)&Vt[BUF][vhalf][d >> 1][0])[(d & 1) * 16 + dwc] = pk;  \
      }                                                                    \
    }                                                                      \
  } while (0)

  // prologue: tile 0 into buffer 0
  LOADREGS(0);
  WRITELDS(0);
  __syncthreads();

  int buf = 0;
  for (int kt = 0; kt < nt; ++kt) {
    const bool more = (kt + 1 < nt);
    if (more) LOADREGS(kt + 1);   // issue global loads; consumed after compute

    __builtin_amdgcn_s_setprio(1);
#pragma unroll
    for (int hh = 0; hh < 2; ++hh) {
      // S^T = K Q^T for 32-key half hh
      f32x4 acc0 = (f32x4){0.f, 0.f, 0.f, 0.f};
      f32x4 acc1 = acc0;
#pragma unroll
      for (int kk = 0; kk < 4; ++kk) {
        bf16x8 a0 = *(const bf16x8*)&Ks[buf][hh * 32 + l15][kk * 32 + quad * 8];
        bf16x8 a1 = *(const bf16x8*)&Ks[buf][hh * 32 + 16 + l15][kk * 32 + quad * 8];
        acc0 = __builtin_amdgcn_mfma_f32_16x16x32_bf16(a0, bq[kk], acc0, 0, 0, 0);
        acc1 = __builtin_amdgcn_mfma_f32_16x16x32_bf16(a1, bq[kk], acc1, 0, 0, 0);
      }

      const uint32_t mword = mw[buf][w * 16 + l15][hh];
      bf16x8 bp;
      float ps = 0.f;
#pragma unroll
      for (int r = 0; r < 4; ++r) {
        const float p0 = ((mword >> (quad * 4 + r)) & 1u) ? __builtin_amdgcn_exp2f(acc0[r]) : 0.f;
        const float p1 = ((mword >> (16 + quad * 4 + r)) & 1u) ? __builtin_amdgcn_exp2f(acc1[r]) : 0.f;
        ps += p0 + p1;
        bp[r] = (short)f2bf(p0);
        bp[4 + r] = (short)f2bf(p1);
      }
      l_lane += ps;

      // O^T += V^T P^T
#pragma unroll
      for (int f = 0; f < 8; ++f) {
        const int d = f * 16 + l15;
        bf16x8 av = *(const bf16x8*)&Vt[buf][hh][d >> 1][(d & 1) * 32 + quad * 8];
        O[f] = __builtin_amdgcn_mfma_f32_16x16x32_bf16(av, bp, O[f], 0, 0, 0);
      }
    }
    __builtin_amdgcn_s_setprio(0);

    if (more) WRITELDS(buf ^ 1);   // other buffer: safe vs concurrent compute(buf)
    __syncthreads();
    buf ^= 1;
  }
#undef LOADREGS
#undef WRITELDS

  l_lane += __shfl_xor(l_lane, 16);
  l_lane += __shfl_xor(l_lane, 32);
  const float rl = 1.0f / l_lane;

  unsigned short* orow = ctx + ((size_t)(b * Lq + q0 + w * 16 + l15)) * Dm + h * DH;
#pragma unroll
  for (int f = 0; f < 8; ++f) {
    ushort4 o4;
    o4.x = f2bf(O[f][0] * rl);
    o4.y = f2bf(O[f][1] * rl);
    o4.z = f2bf(O[f][2] * rl);
    o4.w = f2bf(O[f][3] * rl);
    *(ushort4*)(orow + f * 16 + quad * 4) = o4;
  }
}

// ---------------------------------------------------------------------------
extern "C" void kernel_launch(void* const* d_in, const int* in_sizes, int n_in,
                              void* d_out, int out_size, void* d_ws, size_t ws_size,
                              hipStream_t stream) {
  const float* hs  = (const float*)d_in[0];
  const float* rel = (const float*)d_in[1];
  const float* Wqr = (const float*)d_in[2];
  const float* Wkr = (const float*)d_in[3];
  const float* Wq  = (const float*)d_in[4];
  const float* Wk  = (const float*)d_in[5];
  const float* Wv  = (const float*)d_in[6];
  const float* Wo  = (const float*)d_in[7];
  float* out = (float*)d_out;

  const int M = Bb * Lq;   // 4096
  const int ND = Dm * Dm;
  char* ws = (char*)d_ws;
  size_t off = 0;
  float* qrel = (float*)(ws + off); off += (size_t)M * DREL * 4;
  float* krel = (float*)(ws + off); off += (size_t)M * DREL * 4;
  uint32_t* maskb = (uint32_t*)(ws + off); off += (size_t)M * (Lq / 32) * 4;
  float* partq = (float*)(ws + off); off += (size_t)RKS * M * DREL * 4;
  float* partk = (float*)(ws + off); off += (size_t)RKS * M * DREL * 4;
  // bf16 staging region; Sbuf (B*L*L fp32 = 33.5 MB) is ALIASED onto its head:
  // Sbuf is consumed by relselect before any bf16 buffer is written (in-order stream).
  float* Sbuf = (float*)(ws + off);
  unsigned short* hsb  = (unsigned short*)(ws + off); off += (size_t)M * Dm * 2;
  unsigned short* qkvb = (unsigned short*)(ws + off); off += (size_t)M * 3 * Dm * 2;
  unsigned short* ctxb = (unsigned short*)(ws + off); off += (size_t)M * Dm * 2;
  unsigned short* Wqkvo = (unsigned short*)(ws + off); off += (size_t)4 * ND * 2;  // Wq,Wk,Wv,Wo contiguous

  const dim3 blk(256);
  const int hsN8 = M * Dm / 8;
  const float QSCALE = 0.08838834764831845f * 1.4426950408889634f;  // DH^-0.5 * log2(e)

  // rel pipeline: fp32-exact projections -> dense triangular scores -> wave select
  relproj2<<<dim3(RKS, M / 128, 2), blk, 0, stream>>>(rel, Wqr, Wkr, partq, partk, M);
  relreduce<<<(M * DREL / 4 + 255) / 256, blk, 0, stream>>>(partq, partk, qrel, krel, M * DREL / 4);
  relscore<<<dim3(Lq / 128, Lq / 128, Bb), blk, 0, stream>>>(qrel, krel, Sbuf);
  relselect<<<M / 4, blk, 0, stream>>>(Sbuf, maskb);

  // bf16 conversions (overwrite Sbuf region only after relselect has consumed it)
  conv_bf16<<<(hsN8 + 255) / 256, blk, 0, stream>>>(hs, hsb, hsN8, 1.0f);
  conv_bf16_w4<<<dim3(ND / 8 / 256, 4), blk, 0, stream>>>(Wq, Wk, Wv, Wo, Wqkvo, QSCALE);

  // fused QKV projection: 128x128 tile, BK=32 triple-buffered, 3 blocks/CU
  // grid = 32*48 = 1536 = exactly 2 rounds of 768 resident slots
  gemmT<true><<<dim3((M / 128) * (3 * Dm / 128)), blk, 0, stream>>>(
      hsb, Wqkvo, qkvb, M, 3 * Dm, Dm);

  // flash attention v3
  attn_flash3<<<dim3(Lq / ATQ, Hh, Bb), dim3(512), 0, stream>>>(qkvb, maskb, ctxb);

  // O projection -> fp32 out: grid = 32*16 = 512 blocks (2 balanced per CU)
  gemmT<false><<<dim3((M / 128) * (Dm / 128)), blk, 0, stream>>>(
      ctxb, Wqkvo + (size_t)3 * ND, out, M, Dm, Dm);
}